// Round 1
// baseline (2426.584 us; speedup 1.0000x reference)
//
#include <hip/hip_runtime.h>

// Sparsemax attention: B=8, L=1024, S=1024, H=16, E=64, D=64, fp32.
// Phase 1: QK^T (scaled) tiled via LDS, scores kept in registers,
//          distributed one L-row per wave (64 lanes x 16 regs).
// Phase 2: sparsemax per row via Newton on candidate list (z > rowmax-1).
// Phase 3: sparse A*V using the candidate list (support is tiny).

constexpr int kB = 8;
constexpr int kL = 1024;
constexpr int kS = 1024;
constexpr int kH = 16;
constexpr int kE = 64;
constexpr int kD = 64;

constexpr int LT    = 16;    // L rows per block
constexpr int JT    = 256;   // S cols staged per K tile
constexpr int KSTR4 = 17;    // LDS row stride in float4 (68 floats) -> conflict-free
constexpr int CAP   = 512;   // candidate list capacity per row (aliases Ks region)

__global__ __launch_bounds__(256, 2)
void sparsemax_attn(const float* __restrict__ Q,
                    const float* __restrict__ K,
                    const float* __restrict__ V,
                    float* __restrict__ O) {
  __shared__ float4 Ks4[JT * KSTR4];   // 69,632 B; later aliased as candidate lists
  __shared__ float4 Qs4[LT * KSTR4];   // 4,352 B

  const int t    = threadIdx.x;
  const int lane = t & 63;
  const int rg   = t >> 6;             // wave id 0..3 (wave rg owns rows rg*4..rg*4+3)
  const int bh   = blockIdx.y;
  const int b    = bh >> 4;
  const int h    = bh & 15;
  const int l0   = blockIdx.x * LT;

  // ---- load Q tile into LDS, folding in the 1/sqrt(E) scale ----
  {
    const int r = t >> 4, e4 = t & 15;
    const float4* qg =
        (const float4*)(Q + (((size_t)(b * kL + l0 + r)) * kH + h) * kE) + e4;
    float4 q = *qg;
    q.x *= 0.125f; q.y *= 0.125f; q.z *= 0.125f; q.w *= 0.125f;
    Qs4[r * KSTR4 + e4] = q;
  }

  // scores: scr[rr][cc] is score for row (rg*4+rr), col j = lane + 64*cc
  float scr[4][16];

#pragma unroll
  for (int jt = 0; jt < kS / JT; ++jt) {
    __syncthreads();
    // stage K tile (JT rows x 64 e): coalesced float4 loads
#pragma unroll
    for (int i = 0; i < 16; ++i) {
      const int f4 = t + 256 * i;              // 0..4095
      const int jj = f4 >> 4, e4 = f4 & 15;
      const float4 kv =
          ((const float4*)(K + (((size_t)(b * kS + jt * JT + jj)) * kH + h) * kE))[e4];
      Ks4[jj * KSTR4 + e4] = kv;
    }
    __syncthreads();

    float acc[4][4] = {};
    for (int e4 = 0; e4 < 16; ++e4) {
      float4 kv[4], qv[4];
#pragma unroll
      for (int c = 0; c < 4; ++c) kv[c] = Ks4[(lane + 64 * c) * KSTR4 + e4];
#pragma unroll
      for (int rr = 0; rr < 4; ++rr) qv[rr] = Qs4[(rg * 4 + rr) * KSTR4 + e4];
#pragma unroll
      for (int rr = 0; rr < 4; ++rr)
#pragma unroll
        for (int c = 0; c < 4; ++c) {
          float a = acc[rr][c];
          a = fmaf(qv[rr].x, kv[c].x, a);
          a = fmaf(qv[rr].y, kv[c].y, a);
          a = fmaf(qv[rr].z, kv[c].z, a);
          a = fmaf(qv[rr].w, kv[c].w, a);
          acc[rr][c] = a;
        }
    }
#pragma unroll
    for (int rr = 0; rr < 4; ++rr)
#pragma unroll
      for (int c = 0; c < 4; ++c) scr[rr][4 * jt + c] = acc[rr][c];
  }
  __syncthreads();  // all waves done reading Ks -> safe to alias as lists

  float2* lists = (float2*)Ks4;  // [16 rows][CAP] of (z, j-as-float): 65,536 B

  float tau[4];
  int   ncand[4];

#pragma unroll
  for (int rr = 0; rr < 4; ++rr) {
    const int r = rg * 4 + rr;
    // ---- row max (lane-local then wave reduce) ----
    float m = scr[rr][0];
#pragma unroll
    for (int cc = 1; cc < 16; ++cc) m = fmaxf(m, scr[rr][cc]);
#pragma unroll
    for (int off = 32; off; off >>= 1) m = fmaxf(m, __shfl_xor(m, off));
    const float thr = m - 1.0f;   // tau* >= rowmax - 1: only z > thr can be in support

    // ---- compact candidates into LDS via ballot prefix ----
    int base = 0;
#pragma unroll
    for (int cc = 0; cc < 16; ++cc) {
      const float z  = scr[rr][cc];
      const bool  nz = z > thr;
      const unsigned long long bal = __ballot(nz);
      if (nz) {
        const int pos = base + __popcll(bal & ((1ull << lane) - 1ull));
        if (pos < CAP)
          lists[r * CAP + pos] = make_float2(z, __int_as_float(lane + 64 * cc));
      }
      base += __popcll(bal);
    }
    ncand[rr] = base;

    // ---- Newton on f(t) = sum(max(z - t, 0)) - 1, from t0 = rowmax - 1 ----
    float t0 = thr;
    if (base <= CAP) {
      float zreg[8];
#pragma unroll
      for (int mi = 0; mi < 8; ++mi) zreg[mi] = -1e30f;
      const int M = (base + 63) >> 6;
      for (int mi = 0; mi < M; ++mi) {
        const int i = lane + 64 * mi;
        if (i < base) zreg[mi] = lists[r * CAP + i].x;
      }
      for (int it = 0; it < 32; ++it) {
        float s = 0.f, c = 0.f;
#pragma unroll
        for (int mi = 0; mi < 8; ++mi) {
          const float d = zreg[mi] - t0;
          if (d > 0.f) { s += d; c += 1.f; }
        }
#pragma unroll
        for (int off = 32; off; off >>= 1) {
          s += __shfl_xor(s, off);
          c += __shfl_xor(c, off);
        }
        const float delta = (s - 1.0f) / c;
        if (delta <= 1e-7f) break;
        t0 += delta;
      }
    } else {
      // dense fallback (pathological rows): Newton over all in-register scores
      for (int it = 0; it < 48; ++it) {
        float s = 0.f, c = 0.f;
#pragma unroll
        for (int cc = 0; cc < 16; ++cc) {
          const float d = scr[rr][cc] - t0;
          if (d > 0.f) { s += d; c += 1.f; }
        }
#pragma unroll
        for (int off = 32; off; off >>= 1) {
          s += __shfl_xor(s, off);
          c += __shfl_xor(c, off);
        }
        const float delta = (s - 1.0f) / c;
        if (delta <= 1e-7f) break;
        t0 += delta;
      }
    }
    tau[rr] = t0;
  }

  // ---- sparse A*V: lane = output dim d; iterate candidate list ----
  const float* Vb = V + ((size_t)b * kS * kH + h) * (size_t)kD;  // V[b][0][h][0]
#pragma unroll
  for (int rr = 0; rr < 4; ++rr) {
    const int   r  = rg * 4 + rr;
    const float tr = tau[rr];
    const int   n  = ncand[rr];
    float acc = 0.f;
    if (n <= CAP) {
      int i = 0;
      for (; i + 4 <= n; i += 4) {
        const float2 e0 = lists[r * CAP + i + 0];
        const float2 e1 = lists[r * CAP + i + 1];
        const float2 e2 = lists[r * CAP + i + 2];
        const float2 e3 = lists[r * CAP + i + 3];
        const float v0 = Vb[(size_t)__float_as_int(e0.y) * (kH * kD) + lane];
        const float v1 = Vb[(size_t)__float_as_int(e1.y) * (kH * kD) + lane];
        const float v2 = Vb[(size_t)__float_as_int(e2.y) * (kH * kD) + lane];
        const float v3 = Vb[(size_t)__float_as_int(e3.y) * (kH * kD) + lane];
        acc = fmaf(fmaxf(e0.x - tr, 0.f), v0, acc);
        acc = fmaf(fmaxf(e1.x - tr, 0.f), v1, acc);
        acc = fmaf(fmaxf(e2.x - tr, 0.f), v2, acc);
        acc = fmaf(fmaxf(e3.x - tr, 0.f), v3, acc);
      }
      for (; i < n; ++i) {
        const float2 e = lists[r * CAP + i];
        const float  v = Vb[(size_t)__float_as_int(e.y) * (kH * kD) + lane];
        acc = fmaf(fmaxf(e.x - tr, 0.f), v, acc);
      }
    } else {
      // dense fallback: broadcast every score from its owner lane
#pragma unroll
      for (int cc = 0; cc < 16; ++cc) {
        for (int src = 0; src < 64; ++src) {
          const float z = __shfl(scr[rr][cc], src);
          const float p = z - tr;
          if (p > 0.f) acc = fmaf(p, Vb[(size_t)(src + 64 * cc) * (kH * kD) + lane], acc);
        }
      }
    }
    O[(((size_t)(b * kL + l0 + r)) * kH + h) * kD + lane] = acc;
  }
}

extern "C" void kernel_launch(void* const* d_in, const int* in_sizes, int n_in,
                              void* d_out, int out_size, void* d_ws, size_t ws_size,
                              hipStream_t stream) {
  (void)in_sizes; (void)n_in; (void)out_size; (void)d_ws; (void)ws_size;
  const float* Q = (const float*)d_in[0];
  const float* K = (const float*)d_in[1];
  const float* V = (const float*)d_in[2];
  float* O = (float*)d_out;
  dim3 grid(kL / LT, kB * kH);
  sparsemax_attn<<<grid, dim3(256), 0, stream>>>(Q, K, V, O);
}

// Round 2
// 1032.606 us; speedup vs baseline: 2.3500x; 2.3500x over previous
//
#include <hip/hip_runtime.h>

// Sparsemax attention: B=8, L=1024, S=1024, H=16, E=64, D=64, fp32.
// Streaming design (no per-thread score array -> no spills):
//   per 256-col K tile: QK^T (fp32, LDS-staged K, XOR-swizzled) -> update
//   running rowmax -> compact candidates (z > rowmax-1) into LDS lists.
//   Then Newton sparsemax on the tiny candidate list, then sparse A*V.

constexpr int kB = 8;
constexpr int kL = 1024;
constexpr int kS = 1024;
constexpr int kH = 16;
constexpr int kE = 64;
constexpr int kD = 64;

constexpr int LT  = 16;    // L rows per block (4 waves x 4 rows)
constexpr int JT  = 256;   // S cols staged per K tile
constexpr int CAP = 88;    // candidate capacity per row (expected ~25)

__global__ __launch_bounds__(256, 2)
void sparsemax_attn(const float* __restrict__ Q,
                    const float* __restrict__ K,
                    const float* __restrict__ V,
                    float* __restrict__ O) {
  __shared__ float4 Ks4[JT * 16];     // 65,536 B, XOR-swizzled (slot e4 ^ (row&7))
  __shared__ float4 Qs4[LT * 16];     //  4,096 B, same swizzle
  __shared__ float2 lists[LT * CAP];  // 11,264 B  (z, j-as-float)

  const int t    = threadIdx.x;
  const int lane = t & 63;
  const int rg   = t >> 6;            // wave id: owns rows rg*4 .. rg*4+3
  const int bh   = blockIdx.y;
  const int b    = bh >> 4;
  const int h    = bh & 15;
  const int l0   = blockIdx.x * LT;

  const float* Kbh = K + ((size_t)b * kS * kH + h) * kE;  // K[b][0][h][0]
  const float* Vb  = V + ((size_t)b * kS * kH + h) * kD;  // V[b][0][h][0]

  // ---- stage Q tile (scale folded), swizzled ----
  {
    const int r = t >> 4, e4 = t & 15;
    float4 q = ((const float4*)(Q + (((size_t)(b * kL + l0 + r)) * kH + h) * kE))[e4];
    q.x *= 0.125f; q.y *= 0.125f; q.z *= 0.125f; q.w *= 0.125f;
    Qs4[r * 16 + (e4 ^ (r & 7))] = q;
  }

  float m[4];
  int   base[4];
#pragma unroll
  for (int rr = 0; rr < 4; ++rr) { m[rr] = -1e30f; base[rr] = 0; }

  for (int jt = 0; jt < kS / JT; ++jt) {
    __syncthreads();   // protect Ks from previous tile's readers (also covers Qs at jt=0)
    // ---- stage K tile: coalesced float4 global loads, swizzled LDS store ----
#pragma unroll
    for (int i = 0; i < 16; ++i) {
      const int f4 = t + 256 * i;
      const int jj = f4 >> 4, e4 = f4 & 15;
      const float4 kv = ((const float4*)(Kbh + (size_t)(jt * JT + jj) * (kH * kE)))[e4];
      Ks4[jj * 16 + (e4 ^ (jj & 7))] = kv;
    }
    __syncthreads();

    // ---- QK^T for this tile: acc[rr][c] = score(row rg*4+rr, col lane+64c) ----
    float acc[4][4] = {};
#pragma unroll 4
    for (int e4 = 0; e4 < 16; ++e4) {
      float4 kv[4], qv[4];
      const int ks = e4 ^ (lane & 7);        // (lane+64c)&7 == lane&7
#pragma unroll
      for (int c = 0; c < 4; ++c) kv[c] = Ks4[(lane + 64 * c) * 16 + ks];
#pragma unroll
      for (int rr = 0; rr < 4; ++rr)
        qv[rr] = Qs4[(rg * 4 + rr) * 16 + (e4 ^ ((rg * 4 + rr) & 7))];
#pragma unroll
      for (int rr = 0; rr < 4; ++rr)
#pragma unroll
        for (int c = 0; c < 4; ++c) {
          float a = acc[rr][c];
          a = fmaf(qv[rr].x, kv[c].x, a);
          a = fmaf(qv[rr].y, kv[c].y, a);
          a = fmaf(qv[rr].z, kv[c].z, a);
          a = fmaf(qv[rr].w, kv[c].w, a);
          acc[rr][c] = a;
        }
    }

    // ---- filter: update running max, compact candidates into lists ----
#pragma unroll
    for (int rr = 0; rr < 4; ++rr) {
      const int r = rg * 4 + rr;
      float tm = fmaxf(fmaxf(acc[rr][0], acc[rr][1]), fmaxf(acc[rr][2], acc[rr][3]));
#pragma unroll
      for (int off = 32; off; off >>= 1) tm = fmaxf(tm, __shfl_xor(tm, off));
      const float mn  = fmaxf(m[rr], tm);
      m[rr] = mn;
      const float thr = mn - 1.0f;
#pragma unroll
      for (int c = 0; c < 4; ++c) {
        const float z  = acc[rr][c];
        const bool  nz = z > thr;
        const unsigned long long bal = __ballot(nz);
        if (nz) {
          const int pos = base[rr] + __popcll(bal & ((1ull << lane) - 1ull));
          if (pos < CAP)
            lists[r * CAP + pos] =
                make_float2(z, __int_as_float(jt * JT + 64 * c + lane));
        }
        base[rr] += __popcll(bal);
      }
    }
  }

  // ---- per-row sparsemax (Newton) + sparse A*V; lane = output dim d ----
#pragma unroll
  for (int rr = 0; rr < 4; ++rr) {
    const int r = rg * 4 + rr;
    const int n = base[rr];

    if (n <= CAP) {
      // Newton on f(t) = sum(max(z-t,0)) - 1 from t0 = rowmax-1 (f >= 0 there)
      const float z0 = (lane < n)      ? lists[r * CAP + lane].x      : -1e30f;
      const float z1 = (lane + 64 < n) ? lists[r * CAP + lane + 64].x : -1e30f;
      float t0 = m[rr] - 1.0f;
      for (int it = 0; it < 24; ++it) {
        const float d0 = z0 - t0, d1 = z1 - t0;
        float s = (d0 > 0.f ? d0 : 0.f) + (d1 > 0.f ? d1 : 0.f);
        float c = (d0 > 0.f ? 1.f : 0.f) + (d1 > 0.f ? 1.f : 0.f);
#pragma unroll
        for (int off = 32; off; off >>= 1) {
          s += __shfl_xor(s, off);
          c += __shfl_xor(c, off);
        }
        const float delta = (s - 1.0f) / c;
        if (delta <= 1e-7f) break;
        t0 += delta;
      }
      const float tau = t0;

      // sparse A*V over the candidate list (coalesced 256B V-row reads)
      float oacc = 0.f;
      int i = 0;
      for (; i + 4 <= n; i += 4) {
        const float2 e0 = lists[r * CAP + i + 0];
        const float2 e1 = lists[r * CAP + i + 1];
        const float2 e2 = lists[r * CAP + i + 2];
        const float2 e3 = lists[r * CAP + i + 3];
        const float v0 = Vb[(size_t)__float_as_int(e0.y) * (kH * kD) + lane];
        const float v1 = Vb[(size_t)__float_as_int(e1.y) * (kH * kD) + lane];
        const float v2 = Vb[(size_t)__float_as_int(e2.y) * (kH * kD) + lane];
        const float v3 = Vb[(size_t)__float_as_int(e3.y) * (kH * kD) + lane];
        oacc = fmaf(fmaxf(e0.x - tau, 0.f), v0, oacc);
        oacc = fmaf(fmaxf(e1.x - tau, 0.f), v1, oacc);
        oacc = fmaf(fmaxf(e2.x - tau, 0.f), v2, oacc);
        oacc = fmaf(fmaxf(e3.x - tau, 0.f), v3, oacc);
      }
      for (; i < n; ++i) {
        const float2 e = lists[r * CAP + i];
        const float  v = Vb[(size_t)__float_as_int(e.y) * (kH * kD) + lane];
        oacc = fmaf(fmaxf(e.x - tau, 0.f), v, oacc);
      }
      O[(((size_t)(b * kL + l0 + r)) * kH + h) * kD + lane] = oacc;
    } else {
      // ---- cold exact fallback (list overflow; statistically never taken) ----
      // recompute full score row from global K + LDS Q
      float scr2[16];
      for (int cc = 0; cc < 16; ++cc) {
        const int j = lane + 64 * cc;
        const float4* kr = (const float4*)(Kbh + (size_t)j * (kH * kE));
        float z = 0.f;
        for (int e4 = 0; e4 < 16; ++e4) {
          const float4 q = Qs4[r * 16 + (e4 ^ (r & 7))];
          const float4 kk = kr[e4];
          z = fmaf(q.x, kk.x, z); z = fmaf(q.y, kk.y, z);
          z = fmaf(q.z, kk.z, z); z = fmaf(q.w, kk.w, z);
        }
        scr2[cc] = z;
      }
      float t0 = m[rr] - 1.0f;
      for (int it = 0; it < 48; ++it) {
        float s = 0.f, c = 0.f;
        for (int cc = 0; cc < 16; ++cc) {
          const float d = scr2[cc] - t0;
          if (d > 0.f) { s += d; c += 1.f; }
        }
#pragma unroll
        for (int off = 32; off; off >>= 1) {
          s += __shfl_xor(s, off);
          c += __shfl_xor(c, off);
        }
        const float delta = (s - 1.0f) / c;
        if (delta <= 1e-7f) break;
        t0 += delta;
      }
      float oacc = 0.f;
      for (int cc = 0; cc < 16; ++cc) {
        for (int src = 0; src < 64; ++src) {
          const float z = __shfl(scr2[cc], src);
          const float p = z - t0;
          if (p > 0.f)
            oacc = fmaf(p, Vb[(size_t)(src + 64 * cc) * (kH * kD) + lane], oacc);
        }
      }
      O[(((size_t)(b * kL + l0 + r)) * kH + h) * kD + lane] = oacc;
    }
  }
}

extern "C" void kernel_launch(void* const* d_in, const int* in_sizes, int n_in,
                              void* d_out, int out_size, void* d_ws, size_t ws_size,
                              hipStream_t stream) {
  (void)in_sizes; (void)n_in; (void)out_size; (void)d_ws; (void)ws_size;
  const float* Q = (const float*)d_in[0];
  const float* K = (const float*)d_in[1];
  const float* V = (const float*)d_in[2];
  float* O = (float*)d_out;
  dim3 grid(kL / LT, kB * kH);
  sparsemax_attn<<<grid, dim3(256), 0, stream>>>(Q, K, V, O);
}

// Round 4
// 622.207 us; speedup vs baseline: 3.9000x; 1.6596x over previous
//
#include <hip/hip_runtime.h>

// Sparsemax attention: B=8, L=1024, S=1024, H=16, E=64, D=64, fp32 in/out.
// QK^T via fp16 MFMA (16x16x32), streaming candidate filter (z > rowmax-1),
// Newton sparsemax on tiny candidate lists, sparse A*V.

typedef _Float16 f16x8 __attribute__((ext_vector_type(8)));
typedef float    f32x4 __attribute__((ext_vector_type(4)));

constexpr int kB = 8, kL = 1024, kS = 1024, kH = 16, kE = 64, kD = 64;
constexpr int LT   = 16;          // L rows per block
constexpr int JT   = 128;         // S cols per staged K tile
constexpr int CAP  = 192;         // candidate capacity per row (expected ~30)
constexpr int KMAX = CAP / 16;    // Newton regs per lane (16 lanes per row)

__device__ __forceinline__ float pk2(float a, float b) {
  auto h = __builtin_amdgcn_cvt_pkrtz(a, b);   // __fp16 ext_vector_type(2)
  return __builtin_bit_cast(float, h);
}

__global__ __launch_bounds__(256, 3)
void sparsemax_attn(const float* __restrict__ Q, const float* __restrict__ K,
                    const float* __restrict__ V, float* __restrict__ O) {
  __shared__ float4 Ksh[JT * 8];       // 16 KB fp16 K tile, swizzled slot^(row&7)
  __shared__ float4 Qsh[LT * 8];       //  2 KB fp16 Q tile (scale folded)
  __shared__ float2 lists[LT * CAP];   // 24 KB (z, j-as-float)
  __shared__ int    cnt_s[LT];
  __shared__ float  rmax_s[LT][4];
  __shared__ float  tau_s[LT];

  const int t = threadIdx.x, lane = t & 63, rg = t >> 6;
  const int li = lane & 15, g = lane >> 4;
  const int bh = blockIdx.y, b = bh >> 4, h = bh & 15;
  const int l0 = blockIdx.x * LT;

  const float* Kbh = K + ((size_t)b * kS * kH + h) * kE;
  const float* Vb  = V + ((size_t)b * kS * kH + h) * kD;

  if (t < LT) cnt_s[t] = 0;
  if (t < 128) {  // stage Q: 16 rows x 8 slots of 8 halfs
    const int jj = t >> 3, e8 = t & 7;
    const float4* qp =
        (const float4*)(Q + (((size_t)(b * kL + l0 + jj)) * kH + h) * kE + e8 * 8);
    float4 q0 = qp[0], q1 = qp[1];
    q0.x *= .125f; q0.y *= .125f; q0.z *= .125f; q0.w *= .125f;
    q1.x *= .125f; q1.y *= .125f; q1.z *= .125f; q1.w *= .125f;
    Qsh[jj * 8 + (e8 ^ (jj & 7))] =
        make_float4(pk2(q0.x, q0.y), pk2(q0.z, q0.w), pk2(q1.x, q1.y), pk2(q1.z, q1.w));
  }

  float run[4] = {-1e30f, -1e30f, -1e30f, -1e30f};
  f16x8 a0, a1;

  for (int jt = 0; jt < kS / JT; ++jt) {
    __syncthreads();
    // stage K tile: 128 rows x 64 halfs; coalesced fp32 loads + pkrtz cvt
#pragma unroll
    for (int i = 0; i < 4; ++i) {
      const int idx = t + 256 * i, jj = idx >> 3, e8 = idx & 7;
      const float4* kp =
          (const float4*)(Kbh + (size_t)(jt * JT + jj) * (kH * kE) + e8 * 8);
      const float4 c0 = kp[0], c1 = kp[1];
      Ksh[jj * 8 + (e8 ^ (jj & 7))] =
          make_float4(pk2(c0.x, c0.y), pk2(c0.z, c0.w), pk2(c1.x, c1.y), pk2(c1.z, c1.w));
    }
    __syncthreads();
    if (jt == 0) {  // a-frags: Q[row=li][k = ks*32 + g*8 ..+8]
      a0 = __builtin_bit_cast(f16x8, Qsh[li * 8 + ((0 + g) ^ (li & 7))]);
      a1 = __builtin_bit_cast(f16x8, Qsh[li * 8 + ((4 + g) ^ (li & 7))]);
    }

    f32x4 acc[2];
    acc[0] = f32x4{0.f, 0.f, 0.f, 0.f};
    acc[1] = f32x4{0.f, 0.f, 0.f, 0.f};
#pragma unroll
    for (int ct = 0; ct < 2; ++ct) {  // wave rg covers cols rg*32 + ct*16 + li
      const int jl = rg * 32 + ct * 16 + li;
      const f16x8 b0 = __builtin_bit_cast(f16x8, Ksh[jl * 8 + ((0 + g) ^ (jl & 7))]);
      const f16x8 b1 = __builtin_bit_cast(f16x8, Ksh[jl * 8 + ((4 + g) ^ (jl & 7))]);
      acc[ct] = __builtin_amdgcn_mfma_f32_16x16x32_f16(a0, b0, acc[ct], 0, 0, 0);
      acc[ct] = __builtin_amdgcn_mfma_f32_16x16x32_f16(a1, b1, acc[ct], 0, 0, 0);
    }

    // filter: C-layout row = g*4+r, col = lane&15 (+ct*16)
#pragma unroll
    for (int r = 0; r < 4; ++r) {
      const int row = g * 4 + r;
      float mr = fmaxf(acc[0][r], acc[1][r]);
      mr = fmaxf(mr, __shfl_xor(mr, 1));
      mr = fmaxf(mr, __shfl_xor(mr, 2));
      mr = fmaxf(mr, __shfl_xor(mr, 4));
      mr = fmaxf(mr, __shfl_xor(mr, 8));
      run[r] = fmaxf(run[r], mr);
      const float thr = run[r] - 1.0f;
#pragma unroll
      for (int ct = 0; ct < 2; ++ct) {
        const float z = acc[ct][r];
        if (z > thr) {
          const int pos = atomicAdd(&cnt_s[row], 1);
          if (pos < CAP)
            lists[row * CAP + pos] =
                make_float2(z, __int_as_float(jt * JT + rg * 32 + ct * 16 + li));
        }
      }
    }
  }
  if (li == 0) {
#pragma unroll
    for (int r = 0; r < 4; ++r) rmax_s[g * 4 + r][rg] = run[r];
  }
  __syncthreads();

  // ---- Newton: wave rg owns rows rg*4..+3; 16 lanes per row concurrently ----
  const int q0 = rg * 4;
  {
    const int row = q0 + g;
    const int n   = cnt_s[row];
    const int nc  = min(n, CAP);
    float zr[KMAX];
#pragma unroll
    for (int k = 0; k < KMAX; ++k) {
      const int i = li + 16 * k;
      zr[k] = (i < nc) ? lists[row * CAP + i].x : -1e30f;
    }
    const float M =
        fmaxf(fmaxf(rmax_s[row][0], rmax_s[row][1]), fmaxf(rmax_s[row][2], rmax_s[row][3]));
    float t0 = M - 1.0f;
    for (int it = 0; it < 14; ++it) {
      float s = 0.f, c = 0.f;
#pragma unroll
      for (int k = 0; k < KMAX; ++k) {
        const float d = zr[k] - t0;
        if (d > 0.f) { s += d; c += 1.f; }
      }
      s += __shfl_xor(s, 1); c += __shfl_xor(c, 1);
      s += __shfl_xor(s, 2); c += __shfl_xor(c, 2);
      s += __shfl_xor(s, 4); c += __shfl_xor(c, 4);
      s += __shfl_xor(s, 8); c += __shfl_xor(c, 8);
      const float delta = (s - 1.0f) / fmaxf(c, 1.f);
      t0 += fmaxf(delta, 0.f);
      if (__all(delta <= 1e-6f)) break;
    }
    if (li == 0) tau_s[row] = t0;
  }

  // ---- sparse A*V: lane = output dim d ----
#pragma unroll 1
  for (int r4 = 0; r4 < 4; ++r4) {
    const int row = q0 + r4;
    const int n   = cnt_s[row];
    float oacc = 0.f;
    if (n <= CAP) {
      const float tau = tau_s[row];
      const float4* lp = (const float4*)(lists + row * CAP);
      const int np = n >> 1;
      int i2 = 0;
      for (; i2 + 2 <= np; i2 += 2) {
        const float4 p0 = lp[i2], p1 = lp[i2 + 1];
        const float v0 = Vb[(size_t)__float_as_int(p0.y) * (kH * kD) + lane];
        const float v1 = Vb[(size_t)__float_as_int(p0.w) * (kH * kD) + lane];
        const float v2 = Vb[(size_t)__float_as_int(p1.y) * (kH * kD) + lane];
        const float v3 = Vb[(size_t)__float_as_int(p1.w) * (kH * kD) + lane];
        oacc = fmaf(fmaxf(p0.x - tau, 0.f), v0, oacc);
        oacc = fmaf(fmaxf(p0.z - tau, 0.f), v1, oacc);
        oacc = fmaf(fmaxf(p1.x - tau, 0.f), v2, oacc);
        oacc = fmaf(fmaxf(p1.z - tau, 0.f), v3, oacc);
      }
      for (; i2 < np; ++i2) {
        const float4 p0 = lp[i2];
        const float v0 = Vb[(size_t)__float_as_int(p0.y) * (kH * kD) + lane];
        const float v1 = Vb[(size_t)__float_as_int(p0.w) * (kH * kD) + lane];
        oacc = fmaf(fmaxf(p0.x - tau, 0.f), v0, oacc);
        oacc = fmaf(fmaxf(p0.z - tau, 0.f), v1, oacc);
      }
      if (n & 1) {
        const float2 e = lists[row * CAP + n - 1];
        oacc = fmaf(fmaxf(e.x - tau, 0.f),
                    Vb[(size_t)__float_as_int(e.y) * (kH * kD) + lane], oacc);
      }
    } else {
      // ---- cold exact fallback (list overflow): dense recompute ----
      float scr2[16];
      for (int cc = 0; cc < 16; ++cc) {
        const int j = lane + 64 * cc;
        const float* kr = Kbh + (size_t)j * (kH * kE);
        float zz = 0.f;
        for (int e8 = 0; e8 < 8; ++e8) {
          const f16x8 qh = __builtin_bit_cast(f16x8, Qsh[row * 8 + (e8 ^ (row & 7))]);
          const float4* kp = (const float4*)(kr + e8 * 8);
          const float4 c0 = kp[0], c1 = kp[1];
          zz += (float)qh[0] * c0.x + (float)qh[1] * c0.y + (float)qh[2] * c0.z +
                (float)qh[3] * c0.w + (float)qh[4] * c1.x + (float)qh[5] * c1.y +
                (float)qh[6] * c1.z + (float)qh[7] * c1.w;
        }
        scr2[cc] = zz;
      }
      const float M2 =
          fmaxf(fmaxf(rmax_s[row][0], rmax_s[row][1]), fmaxf(rmax_s[row][2], rmax_s[row][3]));
      float t0 = M2 - 1.0f;
      for (int it = 0; it < 48; ++it) {
        float s = 0.f, c = 0.f;
        for (int cc = 0; cc < 16; ++cc) {
          const float d = scr2[cc] - t0;
          if (d > 0.f) { s += d; c += 1.f; }
        }
        for (int off = 32; off; off >>= 1) { s += __shfl_xor(s, off); c += __shfl_xor(c, off); }
        const float delta = (s - 1.0f) / fmaxf(c, 1.f);
        if (delta <= 1e-7f) break;
        t0 += delta;
      }
      for (int cc = 0; cc < 16; ++cc)
        for (int src = 0; src < 64; ++src) {
          const float z = __shfl(scr2[cc], src);
          const float p = z - t0;
          if (p > 0.f)
            oacc = fmaf(p, Vb[(size_t)(src + 64 * cc) * (kH * kD) + lane], oacc);
        }
    }
    O[(((size_t)(b * kL + l0 + row)) * kH + h) * kD + lane] = oacc;
  }
}

extern "C" void kernel_launch(void* const* d_in, const int* in_sizes, int n_in,
                              void* d_out, int out_size, void* d_ws, size_t ws_size,
                              hipStream_t stream) {
  (void)in_sizes; (void)n_in; (void)out_size; (void)d_ws; (void)ws_size;
  const float* Q = (const float*)d_in[0];
  const float* K = (const float*)d_in[1];
  const float* V = (const float*)d_in[2];
  float* O = (float*)d_out;
  dim3 grid(kL / LT, kB * kH);
  sparsemax_attn<<<grid, dim3(256), 0, stream>>>(Q, K, V, O);
}